// Round 15
// baseline (37.928 us; speedup 1.0000x reference)
//
#include <hip/hip_runtime.h>

#define N_    4
#define CIN   64
#define COUT  64
#define H_    128
#define W_    128
#define HO_   128
#define WO_   128
#define K2_   9

// staged halo region: rows [hb-5, hb+12] (18), cols [wb-5, wb+20] (26)
#define RROWS 18
#define RCOLS 26

typedef __attribute__((ext_vector_type(8))) short  short8;   // 8 bf16 (4 VGPRs)
typedef __attribute__((ext_vector_type(4))) float  f32x4;    // MFMA accumulator

__device__ __forceinline__ unsigned short f32_to_bf16_rne(float f) {
    unsigned int u = __float_as_uint(f);
    u += 0x7fffu + ((u >> 16) & 1u);
    return (unsigned short)(u >> 16);
}
__device__ __forceinline__ unsigned int pk_bf16(float lo, float hi) {
    unsigned int r;
    asm("v_cvt_pk_bf16_f32 %0, %1, %2" : "=v"(r) : "v"(lo), "v"(hi));
    return r;
}
__device__ __forceinline__ float bflo(unsigned int u) { return __uint_as_float(u << 16); }
__device__ __forceinline__ float bfhi(unsigned int u) { return __uint_as_float(u & 0xffff0000u); }

// bilinear combine of one packed pair (2 ci) across 4 corners -> packed bf16
__device__ __forceinline__ unsigned int comb1(
    unsigned int a00, unsigned int a01, unsigned int a10, unsigned int a11,
    float w00, float w01, float w10, float w11) {
    float lo = w00 * bflo(a00) + w01 * bflo(a01) + w10 * bflo(a10) + w11 * bflo(a11);
    float hi = w00 * bfhi(a00) + w01 * bfhi(a01) + w10 * bfhi(a10) + w11 * bfhi(a11);
    return pk_bf16(lo, hi);
}

// single source of truth for the region swizzle: px-block p, 16B-chunk c (0..7)
__device__ __forceinline__ int reg_byteoff(int p, int c) {
    return p * 128 + (((c ^ p) & 7) << 4);
}

// Fused prep: blocks [0,4096) do NCHW f32 -> NHWC bf16; blocks [4096,4240)
// pack weights into MFMA A-fragment order. One launch instead of two.
__global__ __launch_bounds__(256) void DeformConv2d_prep(
    const float* __restrict__ x, const float* __restrict__ w,
    unsigned short* __restrict__ xtb, unsigned short* __restrict__ wfb) {
    const int b = blockIdx.x;
    if (b < 4096) {
        __shared__ float tile[64][17];
        const int xs = (b & 7) << 4;
        const int y  = (b >> 3) & 127;
        const int n  = b >> 10;
        const int t  = threadIdx.x;
        const int xi = t & 15, c0 = t >> 4;
#pragma unroll
        for (int p = 0; p < 4; ++p) {
            int c = c0 + p * 16;
            tile[c][xi] = x[((size_t)(n * 64 + c) * 128 + y) * 128 + xs + xi];
        }
        __syncthreads();
        unsigned int* xq = (unsigned int*)xtb;
        const int cw2 = t & 31, x4 = t >> 5;   // x4: 0..7
#pragma unroll
        for (int q = 0; q < 2; ++q) {
            int xw = q * 8 + x4;
            unsigned int pk = pk_bf16(tile[2 * cw2][xw], tile[2 * cw2 + 1][xw]);
            xq[((size_t)((n * 128 + y) * 128) + xs + xw) * 32 + cw2] = pk;
        }
    } else {
        // wf[((k*4 + t)*2 + kk)*512 + lane*8 + j] = W[co=16t+(l&15)][ci=32kk+(l>>4)*8+j] at tap k
        int i = (b - 4096) * 256 + threadIdx.x;       // 0..36863
        if (i < COUT * CIN * K2_) {
            int j  = i & 7;
            int l  = (i >> 3) & 63;
            int kk = (i >> 9) & 1;
            int t  = (i >> 10) & 3;
            int k  = i >> 12;
            int co = 16 * t + (l & 15);
            int ci = 32 * kk + ((l >> 4) << 3) + j;
            wfb[i] = f32_to_bf16_rne(w[(co * CIN + ci) * K2_ + k]);
        }
    }
}

// Round 15: R14 main kernel + ONE change — 2-slot corner prefetch. Tap k+1's
// weight calc + 8 corner ds_read_b128 issue BEFORE tap k's combine+MFMA
// (~500cy of independent work), so the ~120cy LDS-read latency hides instead
// of stalling each tap's head. Barrier skeleton, Adbuf A-path, params-1-ahead,
// epilogue: all identical to the passing R14.
__global__ __launch_bounds__(512, 4) void DeformConv2d_mfma(
    const float* __restrict__ offset,       // [N,2*K2,HO,WO]
    const float* __restrict__ mask,         // [N,K2,HO,WO]
    const unsigned short* __restrict__ wf,  // bf16 A-fragments [9][512] short8
    const unsigned short* __restrict__ xtb, // bf16 NHWC [N,H,W,CIN]
    float* __restrict__ out)                // [N,COUT,HO,WO] f32
{
    __shared__ short8 Adbuf[2][512];            // 16 KB A double buffer
    __shared__ uint4  Xr4[RROWS * RCOLS * 8];   // 59904 B halo region

    const int tid  = threadIdx.x;
    const int lane = tid & 63;
    const int wv   = tid >> 6;              // 0..7 -> ho row
    const int g    = lane >> 4;             // ci group
    const int pxw  = lane & 15;             // wo offset within wave
    const int ci0  = g * 8;

    // Bijective XCD chunk swizzle (512 % 8 == 0): 64 consecutive per XCD.
    const int raw = blockIdx.x;
    const int swz = (raw & 7) * 64 + (raw >> 3);
    const int n   = swz >> 7;               // 0..3
    const int r   = swz & 127;
    const int hb  = (r >> 3) << 3;          // 0..120 step 8
    const int wb  = (r & 7) << 4;           // 0..112 step 16
    const int ho  = hb + wv;
    const int wo  = wb + pxw;
    const int rowbase = hb - 5;
    const int colbase = wb - 5;

    const unsigned short* xb = xtb + (size_t)n * (H_ * W_ * CIN);
    const short8* wfq = (const short8*)wf;  // [9][512]
    char* XrB = (char*)Xr4;

    // ---- stage halo region (coalesced) + tap-0 A-fragments ----
    {
        const int NCHUNK = RROWS * RCOLS * 8;   // 3744
#pragma unroll
        for (int e = 0; e < 8; ++e) {
            int q = e * 512 + tid;
            if (q < NCHUNK) {
                int p = q >> 3, c = q & 7;
                int i = p / RCOLS, j = p - i * RCOLS;
                int sy = min(max(rowbase + i, 0), H_ - 1);
                int sx = min(max(colbase + j, 0), W_ - 1);
                const uint4 v = *(const uint4*)(xb + (sy * W_ + sx) * CIN + c * 8);
                *(uint4*)(XrB + reg_byteoff(p, c)) = v;
            }
        }
        Adbuf[0][tid] = wfq[tid];
    }

    f32x4 acc[4];
#pragma unroll
    for (int t = 0; t < 4; ++t) acc[t] = (f32x4){0.f, 0.f, 0.f, 0.f};

    const int pofs = ho * WO_ + wo;
    float npdy = offset[(n * 18 + 0) * (HO_ * WO_) + pofs];
    float npdx = offset[(n * 18 + 1) * (HO_ * WO_) + pofs];
    float npm  = mask  [(n * 9  + 0) * (HO_ * WO_) + pofs];

    __syncthreads();    // region + A0 ready

    // ---- 2-slot corner pipeline state ----
    uint4 cva[2][4], cvb[2][4];   // [slot][corner], kk=0 / kk=1 halves
    float cw4[2][4];              // per-slot bilinear weights

    // compute tap-k params (consumes np*), store weights to cw4[s],
    // issue the 8 corner LDS reads into slot s (region is read-only: safe any time)
    auto issue_tap = [&](int k, int s) {
        const int KI = k / 3, KJ = k % 3;
        const float yy  = (float)(ho - 1 + KI) + npdy;
        const float xx  = (float)(wo - 1 + KJ) + npdx;
        const float y0f = floorf(yy), x0f = floorf(xx);
        const int   y0  = (int)y0f,  x0  = (int)x0f;
        const float fy  = yy - y0f,  fx  = xx - x0f;
        const bool yv0 = (y0 >= 0)  && (y0 < H_);
        const bool yv1 = (y0 >= -1) && (y0 < H_ - 1);
        const bool xv0 = (x0 >= 0)  && (x0 < W_);
        const bool xv1 = (x0 >= -1) && (x0 < W_ - 1);
        const float gy0 = (1.f - fy) * npm, gy1 = fy * npm;
        cw4[s][0] = (yv0 && xv0) ? gy0 * (1.f - fx) : 0.f;
        cw4[s][1] = (yv0 && xv1) ? gy0 * fx         : 0.f;
        cw4[s][2] = (yv1 && xv0) ? gy1 * (1.f - fx) : 0.f;
        cw4[s][3] = (yv1 && xv1) ? gy1 * fx         : 0.f;
        const int y0c = min(max(y0, 0), H_ - 1), y1c = min(max(y0 + 1, 0), H_ - 1);
        const int x0c = min(max(x0, 0), W_ - 1), x1c = min(max(x0 + 1, 0), W_ - 1);
        const int cys[2] = { y0c, y1c };
        const int cxs[2] = { x0c, x1c };
#pragma unroll
        for (int cy_i = 0; cy_i < 2; ++cy_i) {
#pragma unroll
            for (int cx_i = 0; cx_i < 2; ++cx_i) {
                const int ci_ = cy_i * 2 + cx_i;
                const int cy = cys[cy_i], cx = cxs[cx_i];
                const int ry = cy - rowbase, rx = cx - colbase;
                const bool in = ((unsigned)ry < (unsigned)RROWS) &&
                                ((unsigned)rx < (unsigned)RCOLS);
                const int p = min(max(ry, 0), RROWS - 1) * RCOLS + min(max(rx, 0), RCOLS - 1);
                uint4 lv0 = *(const uint4*)(XrB + reg_byteoff(p, g));
                uint4 lv1 = *(const uint4*)(XrB + reg_byteoff(p, 4 + g));
                if (!__all((int)in)) {          // wave-uniform rare path
                    const unsigned short* gp = xb + (cy * W_ + cx) * CIN + ci0;
                    uint4 gv0 = *(const uint4*)(gp);
                    uint4 gv1 = *(const uint4*)(gp + 32);
                    if (!in) { lv0 = gv0; lv1 = gv1; }   // exec-masked per lane
                }
                cva[s][ci_] = lv0;
                cvb[s][ci_] = lv1;
            }
        }
    };

    // prologue: tap-0 corners into slot 0; then params for tap 1 in flight
    issue_tap(0, 0);
    npdy = offset[(n * 18 + 2) * (HO_ * WO_) + pofs];
    npdx = offset[(n * 18 + 3) * (HO_ * WO_) + pofs];
    npm  = mask  [(n * 9  + 1) * (HO_ * WO_) + pofs];

#pragma unroll
    for (int k = 0; k < K2_; ++k) {
        // A prefetch for next tap (write-late after MFMA; R6 discipline)
        short8 sA;
        if (k < K2_ - 1) sA = wfq[(k + 1) * 512 + tid];

        // prefetch tap k+1: weights + corner LDS reads into alternate slot,
        // then issue params for tap k+2
        if (k < K2_ - 1) {
            issue_tap(k + 1, (k + 1) & 1);
            if (k + 2 < K2_) {
                npdy = offset[(n * 18 + 2 * (k + 2))     * (HO_ * WO_) + pofs];
                npdx = offset[(n * 18 + 2 * (k + 2) + 1) * (HO_ * WO_) + pofs];
                npm  = mask  [(n * 9  + (k + 2))         * (HO_ * WO_) + pofs];
            }
        }

        // ---- combine slot k&1 -> B fragments (bf16) ----
        const int s = k & 1;
        const float w00 = cw4[s][0], w01 = cw4[s][1], w10 = cw4[s][2], w11 = cw4[s][3];
        union F8 { unsigned int u[4]; short8 v; } f0, f1;
        f0.u[0] = comb1(cva[s][0].x, cva[s][1].x, cva[s][2].x, cva[s][3].x, w00, w01, w10, w11);
        f0.u[1] = comb1(cva[s][0].y, cva[s][1].y, cva[s][2].y, cva[s][3].y, w00, w01, w10, w11);
        f0.u[2] = comb1(cva[s][0].z, cva[s][1].z, cva[s][2].z, cva[s][3].z, w00, w01, w10, w11);
        f0.u[3] = comb1(cva[s][0].w, cva[s][1].w, cva[s][2].w, cva[s][3].w, w00, w01, w10, w11);
        f1.u[0] = comb1(cvb[s][0].x, cvb[s][1].x, cvb[s][2].x, cvb[s][3].x, w00, w01, w10, w11);
        f1.u[1] = comb1(cvb[s][0].y, cvb[s][1].y, cvb[s][2].y, cvb[s][3].y, w00, w01, w10, w11);
        f1.u[2] = comb1(cvb[s][0].z, cvb[s][1].z, cvb[s][2].z, cvb[s][3].z, w00, w01, w10, w11);
        f1.u[3] = comb1(cvb[s][0].w, cvb[s][1].w, cvb[s][2].w, cvb[s][3].w, w00, w01, w10, w11);

        // ---- MFMA: 4 co-tiles x 2 k-halves ----
#pragma unroll
        for (int t = 0; t < 4; ++t) {
            const short8 A0 = Adbuf[k & 1][(t * 2 + 0) * 64 + lane];
            const short8 A1 = Adbuf[k & 1][(t * 2 + 1) * 64 + lane];
            acc[t] = __builtin_amdgcn_mfma_f32_16x16x32_bf16(A0, f0.v, acc[t], 0, 0, 0);
            acc[t] = __builtin_amdgcn_mfma_f32_16x16x32_bf16(A1, f1.v, acc[t], 0, 0, 0);
        }

        // write-late A-stage + single barrier per tap
        if (k < K2_ - 1) {
            Adbuf[(k + 1) & 1][tid] = sA;
            __syncthreads();
        }
    }

    // epilogue: D col = lane&15 (px/wo), row = g*4 + reg (co within tile t)
#pragma unroll
    for (int t = 0; t < 4; ++t) {
#pragma unroll
        for (int rr = 0; rr < 4; ++rr) {
            out[((size_t)(n * COUT + 16 * t + g * 4 + rr) * HO_ + ho) * WO_ + wo] = acc[t][rr];
        }
    }
}

// fp32 fallback (no workspace): known-correct round-1 structure.
__global__ __launch_bounds__(256, 4) void DeformConv2d_fallback(
    const float* __restrict__ x, const float* __restrict__ offset,
    const float* __restrict__ mask, const float* __restrict__ weight,
    float* __restrict__ out)
{
    __shared__ float W_lds[CIN * COUT];
    __shared__ float S_lds[CIN * 68];
    __shared__ float cfy[64], cfx[64], cm[64];
    __shared__ int   cy0[64], cx0[64];

    const int tid = threadIdx.x;
    const int raw = blockIdx.x;
    const int swz = (raw & 7) * 128 + (raw >> 3);
    const int n   = swz >> 8;
    const int r   = swz & 255;
    const int hb  = (r >> 3) << 2;
    const int wb  = (r & 7) << 4;
    const int tr = tid >> 4, tc = tid & 15;

    float acc[4][4];
#pragma unroll
    for (int j = 0; j < 4; ++j)
#pragma unroll
        for (int i = 0; i < 4; ++i) acc[j][i] = 0.f;

    for (int k = 0; k < K2_; ++k) {
        __syncthreads();
        if (tid < 64) {
            const int px = tid, ho = hb + (px >> 4), wo = wb + (px & 15);
            const int ki = k / 3, kj = k % 3;
            const float dy = offset[((n * 18 + 2 * k)     * HO_ + ho) * WO_ + wo];
            const float dx = offset[((n * 18 + 2 * k + 1) * HO_ + ho) * WO_ + wo];
            const float m  = mask  [((n * 9  + k)         * HO_ + ho) * WO_ + wo];
            const float yy = (float)(ho - 1 + ki) + dy;
            const float xx = (float)(wo - 1 + kj) + dx;
            const float y0f = floorf(yy), x0f = floorf(xx);
            cy0[px] = (int)y0f; cx0[px] = (int)x0f;
            cfy[px] = yy - y0f; cfx[px] = xx - x0f; cm[px] = m;
        }
#pragma unroll
        for (int e = 0; e < 16; ++e) {
            int i = e * 256 + tid, ci = i >> 6, co = i & 63;
            W_lds[ci * 64 + co] = weight[(co * CIN + ci) * K2_ + k];
        }
        __syncthreads();
#pragma unroll
        for (int e = 0; e < 16; ++e) {
            int i = e * 256 + tid, ci = i >> 6, px = i & 63;
            int   y0 = cy0[px], x0 = cx0[px];
            float fy = cfy[px], fx = cfx[px], m = cm[px];
            const float* xc = x + (size_t)(n * CIN + ci) * (H_ * W_);
            bool yv0 = (y0 >= 0)  && (y0 < H_);
            bool yv1 = (y0 >= -1) && (y0 < H_ - 1);
            bool xv0 = (x0 >= 0)  && (x0 < W_);
            bool xv1 = (x0 >= -1) && (x0 < W_ - 1);
            float v00 = (yv0 && xv0) ? xc[y0 * W_ + x0]           : 0.f;
            float v01 = (yv0 && xv1) ? xc[y0 * W_ + x0 + 1]       : 0.f;
            float v10 = (yv1 && xv0) ? xc[(y0 + 1) * W_ + x0]     : 0.f;
            float v11 = (yv1 && xv1) ? xc[(y0 + 1) * W_ + x0 + 1] : 0.f;
            float v = (v00 * (1.f - fy) + v10 * fy) * (1.f - fx)
                    + (v01 * (1.f - fy) + v11 * fy) * fx;
            S_lds[ci * 68 + px] = v * m;
        }
        __syncthreads();
#pragma unroll 8
        for (int ci = 0; ci < CIN; ++ci) {
            const float4 a = *(const float4*)&W_lds[ci * 64 + tr * 4];
            const float4 b = *(const float4*)&S_lds[ci * 68 + tc * 4];
            acc[0][0] += a.x * b.x; acc[0][1] += a.x * b.y; acc[0][2] += a.x * b.z; acc[0][3] += a.x * b.w;
            acc[1][0] += a.y * b.x; acc[1][1] += a.y * b.y; acc[1][2] += a.y * b.z; acc[1][3] += a.y * b.w;
            acc[2][0] += a.z * b.x; acc[2][1] += a.z * b.y; acc[2][2] += a.z * b.z; acc[2][3] += a.z * b.w;
            acc[3][0] += a.w * b.x; acc[3][1] += a.w * b.y; acc[3][2] += a.w * b.z; acc[3][3] += a.w * b.w;
        }
    }
    const int co0 = tr * 4, hoE = hb + (tc >> 2), woE = wb + (tc & 3) * 4;
#pragma unroll
    for (int j = 0; j < 4; ++j) {
        float4 v; v.x = acc[j][0]; v.y = acc[j][1]; v.z = acc[j][2]; v.w = acc[j][3];
        *(float4*)&out[((size_t)(n * COUT + co0 + j) * HO_ + hoE) * WO_ + woE] = v;
    }
}

extern "C" void kernel_launch(void* const* d_in, const int* in_sizes, int n_in,
                              void* d_out, int out_size, void* d_ws, size_t ws_size,
                              hipStream_t stream) {
    const float* x      = (const float*)d_in[0];
    const float* offset = (const float*)d_in[1];
    const float* mask   = (const float*)d_in[2];
    const float* weight = (const float*)d_in[3];
    float* out = (float*)d_out;

    const size_t wf_bytes = (size_t)K2_ * 8 * 64 * 8 * sizeof(unsigned short);        // 73728
    const size_t xt_bytes = (size_t)N_ * H_ * W_ * CIN * sizeof(unsigned short);      // 8 MB

    if (ws_size >= wf_bytes + xt_bytes) {
        unsigned short* wfb = (unsigned short*)d_ws;
        unsigned short* xtb = (unsigned short*)((char*)d_ws + wf_bytes);
        DeformConv2d_prep<<<4096 + 144, 256, 0, stream>>>(x, weight, xtb, wfb);
        DeformConv2d_mfma<<<512, 512, 0, stream>>>(offset, mask, wfb, xtb, out);
    } else {
        DeformConv2d_fallback<<<1024, 256, 0, stream>>>(x, offset, mask, weight, out);
    }
}

// Round 16
// 35.466 us; speedup vs baseline: 1.0694x; 1.0694x over previous
//
#include <hip/hip_runtime.h>

#define N_    4
#define CIN   64
#define COUT  64
#define H_    128
#define W_    128
#define HO_   128
#define WO_   128
#define K2_   9

// staged halo region: rows [hb-5, hb+12] (18), cols [wb-5, wb+20] (26)
#define RROWS 18
#define RCOLS 26

typedef __attribute__((ext_vector_type(8))) short  short8;   // 8 bf16 (4 VGPRs)
typedef __attribute__((ext_vector_type(4))) float  f32x4;    // MFMA accumulator

__device__ __forceinline__ unsigned short f32_to_bf16_rne(float f) {
    unsigned int u = __float_as_uint(f);
    u += 0x7fffu + ((u >> 16) & 1u);
    return (unsigned short)(u >> 16);
}
__device__ __forceinline__ unsigned int pk_bf16(float lo, float hi) {
    unsigned int r;
    asm("v_cvt_pk_bf16_f32 %0, %1, %2" : "=v"(r) : "v"(lo), "v"(hi));
    return r;
}
__device__ __forceinline__ float bflo(unsigned int u) { return __uint_as_float(u << 16); }
__device__ __forceinline__ float bfhi(unsigned int u) { return __uint_as_float(u & 0xffff0000u); }

// bilinear combine of one packed pair (2 ci) across 4 corners -> packed bf16
__device__ __forceinline__ unsigned int comb1(
    unsigned int a00, unsigned int a01, unsigned int a10, unsigned int a11,
    float w00, float w01, float w10, float w11) {
    float lo = w00 * bflo(a00) + w01 * bflo(a01) + w10 * bflo(a10) + w11 * bflo(a11);
    float hi = w00 * bfhi(a00) + w01 * bfhi(a01) + w10 * bfhi(a10) + w11 * bfhi(a11);
    return pk_bf16(lo, hi);
}

// single source of truth for the region swizzle: px-block p, 16B-chunk c (0..7)
__device__ __forceinline__ int reg_byteoff(int p, int c) {
    return p * 128 + (((c ^ p) & 7) << 4);
}

// Fused prep: blocks [0,4096) do NCHW f32 -> NHWC bf16; blocks [4096,4240)
// pack weights into MFMA A-fragment order. One launch instead of two.
__global__ __launch_bounds__(256) void DeformConv2d_prep(
    const float* __restrict__ x, const float* __restrict__ w,
    unsigned short* __restrict__ xtb, unsigned short* __restrict__ wfb) {
    const int b = blockIdx.x;
    if (b < 4096) {
        __shared__ float tile[64][17];
        const int xs = (b & 7) << 4;
        const int y  = (b >> 3) & 127;
        const int n  = b >> 10;
        const int t  = threadIdx.x;
        const int xi = t & 15, c0 = t >> 4;
#pragma unroll
        for (int p = 0; p < 4; ++p) {
            int c = c0 + p * 16;
            tile[c][xi] = x[((size_t)(n * 64 + c) * 128 + y) * 128 + xs + xi];
        }
        __syncthreads();
        unsigned int* xq = (unsigned int*)xtb;
        const int cw2 = t & 31, x4 = t >> 5;   // x4: 0..7
#pragma unroll
        for (int q = 0; q < 2; ++q) {
            int xw = q * 8 + x4;
            unsigned int pk = pk_bf16(tile[2 * cw2][xw], tile[2 * cw2 + 1][xw]);
            xq[((size_t)((n * 128 + y) * 128) + xs + xw) * 32 + cw2] = pk;
        }
    } else {
        // wf[((k*4 + t)*2 + kk)*512 + lane*8 + j] = W[co=16t+(l&15)][ci=32kk+(l>>4)*8+j] at tap k
        int i = (b - 4096) * 256 + threadIdx.x;       // 0..36863
        if (i < COUT * CIN * K2_) {
            int j  = i & 7;
            int l  = (i >> 3) & 63;
            int kk = (i >> 9) & 1;
            int t  = (i >> 10) & 3;
            int k  = i >> 12;
            int co = 16 * t + (l & 15);
            int ci = 32 * kk + ((l >> 4) << 3) + j;
            wfb[i] = f32_to_bf16_rne(w[(co * CIN + ci) * K2_ + k]);
        }
    }
}

// Round 16: R14 main kernel + ONE change — ALL 27 offset/mask params preloaded
// at entry (27 independent dword loads, one wait), deleting the rolling
// per-tap param loads whose L2 latency was exposed at every tap head (and
// forced into each tap by the pre-barrier vmcnt(0) drain). Everything else
// (region gather, Adbuf double-buffer, barrier skeleton, epilogue) is the
// passing R14 byte-for-byte.
__global__ __launch_bounds__(512, 4) void DeformConv2d_mfma(
    const float* __restrict__ offset,       // [N,2*K2,HO,WO]
    const float* __restrict__ mask,         // [N,K2,HO,WO]
    const unsigned short* __restrict__ wf,  // bf16 A-fragments [9][512] short8
    const unsigned short* __restrict__ xtb, // bf16 NHWC [N,H,W,CIN]
    float* __restrict__ out)                // [N,COUT,HO,WO] f32
{
    __shared__ short8 Adbuf[2][512];            // 16 KB A double buffer
    __shared__ uint4  Xr4[RROWS * RCOLS * 8];   // 59904 B halo region

    const int tid  = threadIdx.x;
    const int lane = tid & 63;
    const int wv   = tid >> 6;              // 0..7 -> ho row
    const int g    = lane >> 4;             // ci group
    const int pxw  = lane & 15;             // wo offset within wave
    const int ci0  = g * 8;

    // Bijective XCD chunk swizzle (512 % 8 == 0): 64 consecutive per XCD.
    const int raw = blockIdx.x;
    const int swz = (raw & 7) * 64 + (raw >> 3);
    const int n   = swz >> 7;               // 0..3
    const int r   = swz & 127;
    const int hb  = (r >> 3) << 3;          // 0..120 step 8
    const int wb  = (r & 7) << 4;           // 0..112 step 16
    const int ho  = hb + wv;
    const int wo  = wb + pxw;
    const int rowbase = hb - 5;
    const int colbase = wb - 5;

    const unsigned short* xb = xtb + (size_t)n * (H_ * W_ * CIN);
    const short8* wfq = (const short8*)wf;  // [9][512]
    char* XrB = (char*)Xr4;

    // ---- stage halo region (coalesced) + tap-0 A-fragments ----
    {
        const int NCHUNK = RROWS * RCOLS * 8;   // 3744
#pragma unroll
        for (int e = 0; e < 8; ++e) {
            int q = e * 512 + tid;
            if (q < NCHUNK) {
                int p = q >> 3, c = q & 7;
                int i = p / RCOLS, j = p - i * RCOLS;
                int sy = min(max(rowbase + i, 0), H_ - 1);
                int sx = min(max(colbase + j, 0), W_ - 1);
                const uint4 v = *(const uint4*)(xb + (sy * W_ + sx) * CIN + c * 8);
                *(uint4*)(XrB + reg_byteoff(p, c)) = v;
            }
        }
        Adbuf[0][tid] = wfq[tid];
    }

    f32x4 acc[4];
#pragma unroll
    for (int t = 0; t < 4; ++t) acc[t] = (f32x4){0.f, 0.f, 0.f, 0.f};

    // ---- preload ALL taps' params (27 independent dword loads, one wait) ----
    const int pofs = ho * WO_ + wo;
    float dyv[K2_], dxv[K2_], mv[K2_];
#pragma unroll
    for (int k = 0; k < K2_; ++k) {
        dyv[k] = offset[(n * 18 + 2 * k)     * (HO_ * WO_) + pofs];
        dxv[k] = offset[(n * 18 + 2 * k + 1) * (HO_ * WO_) + pofs];
        mv[k]  = mask  [(n * 9  + k)         * (HO_ * WO_) + pofs];
    }

    __syncthreads();    // region + A0 ready

#pragma unroll
    for (int k = 0; k < K2_; ++k) {
        // A prefetch for next tap (write-late after MFMA; R6 discipline)
        short8 sA;
        if (k < K2_ - 1) sA = wfq[(k + 1) * 512 + tid];

        // params for tap k (registers — no load latency at the tap head)
        const int KI = k / 3, KJ = k % 3;
        const float yy  = (float)(ho - 1 + KI) + dyv[k];
        const float xx  = (float)(wo - 1 + KJ) + dxv[k];
        const float y0f = floorf(yy), x0f = floorf(xx);
        const int   y0  = (int)y0f,  x0  = (int)x0f;
        const float fy  = yy - y0f,  fx  = xx - x0f;
        const bool yv0 = (y0 >= 0)  && (y0 < H_);
        const bool yv1 = (y0 >= -1) && (y0 < H_ - 1);
        const bool xv0 = (x0 >= 0)  && (x0 < W_);
        const bool xv1 = (x0 >= -1) && (x0 < W_ - 1);
        const float gy0 = (1.f - fy) * mv[k], gy1 = fy * mv[k];
        const float w00 = (yv0 && xv0) ? gy0 * (1.f - fx) : 0.f;
        const float w01 = (yv0 && xv1) ? gy0 * fx         : 0.f;
        const float w10 = (yv1 && xv0) ? gy1 * (1.f - fx) : 0.f;
        const float w11 = (yv1 && xv1) ? gy1 * fx         : 0.f;
        const int y0c = min(max(y0, 0), H_ - 1), y1c = min(max(y0 + 1, 0), H_ - 1);
        const int x0c = min(max(x0, 0), W_ - 1), x1c = min(max(x0 + 1, 0), W_ - 1);

        // ---- 4 corners from LDS region (both ci halves), rare global fallback ----
        uint4 cva[4], cvb[4];   // [corner] kk=0 / kk=1
        const int cys[2] = { y0c, y1c };
        const int cxs[2] = { x0c, x1c };
#pragma unroll
        for (int cy_i = 0; cy_i < 2; ++cy_i) {
#pragma unroll
            for (int cx_i = 0; cx_i < 2; ++cx_i) {
                const int ci_ = cy_i * 2 + cx_i;
                const int cy = cys[cy_i], cx = cxs[cx_i];
                const int ry = cy - rowbase, rx = cx - colbase;
                const bool in = ((unsigned)ry < (unsigned)RROWS) &&
                                ((unsigned)rx < (unsigned)RCOLS);
                const int p = min(max(ry, 0), RROWS - 1) * RCOLS + min(max(rx, 0), RCOLS - 1);
                uint4 lv0 = *(const uint4*)(XrB + reg_byteoff(p, g));
                uint4 lv1 = *(const uint4*)(XrB + reg_byteoff(p, 4 + g));
                if (!__all((int)in)) {          // wave-uniform rare path
                    const unsigned short* gp = xb + (cy * W_ + cx) * CIN + ci0;
                    uint4 gv0 = *(const uint4*)(gp);
                    uint4 gv1 = *(const uint4*)(gp + 32);
                    if (!in) { lv0 = gv0; lv1 = gv1; }   // exec-masked per lane
                }
                cva[ci_] = lv0;
                cvb[ci_] = lv1;
            }
        }

        // ---- combine -> B fragments (bf16) ----
        union F8 { unsigned int u[4]; short8 s; } f0, f1;
        f0.u[0] = comb1(cva[0].x, cva[1].x, cva[2].x, cva[3].x, w00, w01, w10, w11);
        f0.u[1] = comb1(cva[0].y, cva[1].y, cva[2].y, cva[3].y, w00, w01, w10, w11);
        f0.u[2] = comb1(cva[0].z, cva[1].z, cva[2].z, cva[3].z, w00, w01, w10, w11);
        f0.u[3] = comb1(cva[0].w, cva[1].w, cva[2].w, cva[3].w, w00, w01, w10, w11);
        f1.u[0] = comb1(cvb[0].x, cvb[1].x, cvb[2].x, cvb[3].x, w00, w01, w10, w11);
        f1.u[1] = comb1(cvb[0].y, cvb[1].y, cvb[2].y, cvb[3].y, w00, w01, w10, w11);
        f1.u[2] = comb1(cvb[0].z, cvb[1].z, cvb[2].z, cvb[3].z, w00, w01, w10, w11);
        f1.u[3] = comb1(cvb[0].w, cvb[1].w, cvb[2].w, cvb[3].w, w00, w01, w10, w11);

        // ---- MFMA: 4 co-tiles x 2 k-halves ----
#pragma unroll
        for (int t = 0; t < 4; ++t) {
            const short8 A0 = Adbuf[k & 1][(t * 2 + 0) * 64 + lane];
            const short8 A1 = Adbuf[k & 1][(t * 2 + 1) * 64 + lane];
            acc[t] = __builtin_amdgcn_mfma_f32_16x16x32_bf16(A0, f0.s, acc[t], 0, 0, 0);
            acc[t] = __builtin_amdgcn_mfma_f32_16x16x32_bf16(A1, f1.s, acc[t], 0, 0, 0);
        }

        // write-late A-stage + single barrier per tap
        if (k < K2_ - 1) {
            Adbuf[(k + 1) & 1][tid] = sA;
            __syncthreads();
        }
    }

    // epilogue: D col = lane&15 (px/wo), row = g*4 + reg (co within tile t)
#pragma unroll
    for (int t = 0; t < 4; ++t) {
#pragma unroll
        for (int rr = 0; rr < 4; ++rr) {
            out[((size_t)(n * COUT + 16 * t + g * 4 + rr) * HO_ + ho) * WO_ + wo] = acc[t][rr];
        }
    }
}

// fp32 fallback (no workspace): known-correct round-1 structure.
__global__ __launch_bounds__(256, 4) void DeformConv2d_fallback(
    const float* __restrict__ x, const float* __restrict__ offset,
    const float* __restrict__ mask, const float* __restrict__ weight,
    float* __restrict__ out)
{
    __shared__ float W_lds[CIN * COUT];
    __shared__ float S_lds[CIN * 68];
    __shared__ float cfy[64], cfx[64], cm[64];
    __shared__ int   cy0[64], cx0[64];

    const int tid = threadIdx.x;
    const int raw = blockIdx.x;
    const int swz = (raw & 7) * 128 + (raw >> 3);
    const int n   = swz >> 8;
    const int r   = swz & 255;
    const int hb  = (r >> 3) << 2;
    const int wb  = (r & 7) << 4;
    const int tr = tid >> 4, tc = tid & 15;

    float acc[4][4];
#pragma unroll
    for (int j = 0; j < 4; ++j)
#pragma unroll
        for (int i = 0; i < 4; ++i) acc[j][i] = 0.f;

    for (int k = 0; k < K2_; ++k) {
        __syncthreads();
        if (tid < 64) {
            const int px = tid, ho = hb + (px >> 4), wo = wb + (px & 15);
            const int ki = k / 3, kj = k % 3;
            const float dy = offset[((n * 18 + 2 * k)     * HO_ + ho) * WO_ + wo];
            const float dx = offset[((n * 18 + 2 * k + 1) * HO_ + ho) * WO_ + wo];
            const float m  = mask  [((n * 9  + k)         * HO_ + ho) * WO_ + wo];
            const float yy = (float)(ho - 1 + ki) + dy;
            const float xx = (float)(wo - 1 + kj) + dx;
            const float y0f = floorf(yy), x0f = floorf(xx);
            cy0[px] = (int)y0f; cx0[px] = (int)x0f;
            cfy[px] = yy - y0f; cfx[px] = xx - x0f; cm[px] = m;
        }
#pragma unroll
        for (int e = 0; e < 16; ++e) {
            int i = e * 256 + tid, ci = i >> 6, co = i & 63;
            W_lds[ci * 64 + co] = weight[(co * CIN + ci) * K2_ + k];
        }
        __syncthreads();
#pragma unroll
        for (int e = 0; e < 16; ++e) {
            int i = e * 256 + tid, ci = i >> 6, px = i & 63;
            int   y0 = cy0[px], x0 = cx0[px];
            float fy = cfy[px], fx = cfx[px], m = cm[px];
            const float* xc = x + (size_t)(n * CIN + ci) * (H_ * W_);
            bool yv0 = (y0 >= 0)  && (y0 < H_);
            bool yv1 = (y0 >= -1) && (y0 < H_ - 1);
            bool xv0 = (x0 >= 0)  && (x0 < W_);
            bool xv1 = (x0 >= -1) && (x0 < W_ - 1);
            float v00 = (yv0 && xv0) ? xc[y0 * W_ + x0]           : 0.f;
            float v01 = (yv0 && xv1) ? xc[y0 * W_ + x0 + 1]       : 0.f;
            float v10 = (yv1 && xv0) ? xc[(y0 + 1) * W_ + x0]     : 0.f;
            float v11 = (yv1 && xv1) ? xc[(y0 + 1) * W_ + x0 + 1] : 0.f;
            float v = (v00 * (1.f - fy) + v10 * fy) * (1.f - fx)
                    + (v01 * (1.f - fy) + v11 * fy) * fx;
            S_lds[ci * 68 + px] = v * m;
        }
        __syncthreads();
#pragma unroll 8
        for (int ci = 0; ci < CIN; ++ci) {
            const float4 a = *(const float4*)&W_lds[ci * 64 + tr * 4];
            const float4 b = *(const float4*)&S_lds[ci * 68 + tc * 4];
            acc[0][0] += a.x * b.x; acc[0][1] += a.x * b.y; acc[0][2] += a.x * b.z; acc[0][3] += a.x * b.w;
            acc[1][0] += a.y * b.x; acc[1][1] += a.y * b.y; acc[1][2] += a.y * b.z; acc[1][3] += a.y * b.w;
            acc[2][0] += a.z * b.x; acc[2][1] += a.z * b.y; acc[2][2] += a.z * b.z; acc[2][3] += a.z * b.w;
            acc[3][0] += a.w * b.x; acc[3][1] += a.w * b.y; acc[3][2] += a.w * b.z; acc[3][3] += a.w * b.w;
        }
    }
    const int co0 = tr * 4, hoE = hb + (tc >> 2), woE = wb + (tc & 3) * 4;
#pragma unroll
    for (int j = 0; j < 4; ++j) {
        float4 v; v.x = acc[j][0]; v.y = acc[j][1]; v.z = acc[j][2]; v.w = acc[j][3];
        *(float4*)&out[((size_t)(n * COUT + co0 + j) * HO_ + hoE) * WO_ + woE] = v;
    }
}

extern "C" void kernel_launch(void* const* d_in, const int* in_sizes, int n_in,
                              void* d_out, int out_size, void* d_ws, size_t ws_size,
                              hipStream_t stream) {
    const float* x      = (const float*)d_in[0];
    const float* offset = (const float*)d_in[1];
    const float* mask   = (const float*)d_in[2];
    const float* weight = (const float*)d_in[3];
    float* out = (float*)d_out;

    const size_t wf_bytes = (size_t)K2_ * 8 * 64 * 8 * sizeof(unsigned short);        // 73728
    const size_t xt_bytes = (size_t)N_ * H_ * W_ * CIN * sizeof(unsigned short);      // 8 MB

    if (ws_size >= wf_bytes + xt_bytes) {
        unsigned short* wfb = (unsigned short*)d_ws;
        unsigned short* xtb = (unsigned short*)((char*)d_ws + wf_bytes);
        DeformConv2d_prep<<<4096 + 144, 256, 0, stream>>>(x, weight, xtb, wfb);
        DeformConv2d_mfma<<<512, 512, 0, stream>>>(offset, mask, wfb, xtb, out);
    } else {
        DeformConv2d_fallback<<<1024, 256, 0, stream>>>(x, offset, mask, weight, out);
    }
}

// Round 17
// 33.413 us; speedup vs baseline: 1.1351x; 1.0614x over previous
//
#include <hip/hip_runtime.h>

#define N_    4
#define CIN   64
#define COUT  64
#define H_    128
#define W_    128
#define HO_   128
#define WO_   128
#define K2_   9

// staged halo region: rows [hb-5, hb+12] (18), cols [wb-5, wb+20] (26)
#define RROWS 18
#define RCOLS 26

typedef __attribute__((ext_vector_type(8))) short  short8;   // 8 bf16 (4 VGPRs)
typedef __attribute__((ext_vector_type(4))) float  f32x4;    // MFMA accumulator

__device__ __forceinline__ unsigned short f32_to_bf16_rne(float f) {
    unsigned int u = __float_as_uint(f);
    u += 0x7fffu + ((u >> 16) & 1u);
    return (unsigned short)(u >> 16);
}
__device__ __forceinline__ unsigned int pk_bf16(float lo, float hi) {
    unsigned int r;
    asm("v_cvt_pk_bf16_f32 %0, %1, %2" : "=v"(r) : "v"(lo), "v"(hi));
    return r;
}
__device__ __forceinline__ float bflo(unsigned int u) { return __uint_as_float(u << 16); }
__device__ __forceinline__ float bfhi(unsigned int u) { return __uint_as_float(u & 0xffff0000u); }

// bilinear combine of one packed pair (2 ci) across 4 corners -> packed bf16
__device__ __forceinline__ unsigned int comb1(
    unsigned int a00, unsigned int a01, unsigned int a10, unsigned int a11,
    float w00, float w01, float w10, float w11) {
    float lo = w00 * bflo(a00) + w01 * bflo(a01) + w10 * bflo(a10) + w11 * bflo(a11);
    float hi = w00 * bfhi(a00) + w01 * bfhi(a01) + w10 * bfhi(a10) + w11 * bfhi(a11);
    return pk_bf16(lo, hi);
}

// single source of truth for the region swizzle: px-block p, 16B-chunk c (0..7)
__device__ __forceinline__ int reg_byteoff(int p, int c) {
    return p * 128 + (((c ^ p) & 7) << 4);
}

// Fused prep: blocks [0,4096) do NCHW f32 -> NHWC bf16; blocks [4096,4240)
// pack weights into MFMA A-fragment order. One launch instead of two.
__global__ __launch_bounds__(256) void DeformConv2d_prep(
    const float* __restrict__ x, const float* __restrict__ w,
    unsigned short* __restrict__ xtb, unsigned short* __restrict__ wfb) {
    const int b = blockIdx.x;
    if (b < 4096) {
        __shared__ float tile[64][17];
        const int xs = (b & 7) << 4;
        const int y  = (b >> 3) & 127;
        const int n  = b >> 10;
        const int t  = threadIdx.x;
        const int xi = t & 15, c0 = t >> 4;
#pragma unroll
        for (int p = 0; p < 4; ++p) {
            int c = c0 + p * 16;
            tile[c][xi] = x[((size_t)(n * 64 + c) * 128 + y) * 128 + xs + xi];
        }
        __syncthreads();
        unsigned int* xq = (unsigned int*)xtb;
        const int cw2 = t & 31, x4 = t >> 5;   // x4: 0..7
#pragma unroll
        for (int q = 0; q < 2; ++q) {
            int xw = q * 8 + x4;
            unsigned int pk = pk_bf16(tile[2 * cw2][xw], tile[2 * cw2 + 1][xw]);
            xq[((size_t)((n * 128 + y) * 128) + xs + xw) * 32 + cw2] = pk;
        }
    } else {
        // wf[((k*4 + t)*2 + kk)*512 + lane*8 + j] = W[co=16t+(l&15)][ci=32kk+(l>>4)*8+j] at tap k
        int i = (b - 4096) * 256 + threadIdx.x;       // 0..36863
        if (i < COUT * CIN * K2_) {
            int j  = i & 7;
            int l  = (i >> 3) & 63;
            int kk = (i >> 9) & 1;
            int t  = (i >> 10) & 3;
            int k  = i >> 12;
            int co = 16 * t + (l & 15);
            int ci = 32 * kk + ((l >> 4) << 3) + j;
            wfb[i] = f32_to_bf16_rne(w[(co * CIN + ci) * K2_ + k]);
        }
    }
}

// Main kernel: the round-14 best (passed, 33.4us total). LDS-gather halo
// region + per-tap A-fragment LDS double buffer with write-late + barrier.
// Session-final: ILP pipelines (R7/R9/R15) get sunk/spilled by the compiler,
// barrier-removal and global-A restructures (R10/R12/R13) NaN'd, param
// preload (R16) regressed — residual ~15us over the pipe floor is exposed
// latency that is not addressable at HIP source level on this structure.
__global__ __launch_bounds__(512, 4) void DeformConv2d_mfma(
    const float* __restrict__ offset,       // [N,2*K2,HO,WO]
    const float* __restrict__ mask,         // [N,K2,HO,WO]
    const unsigned short* __restrict__ wf,  // bf16 A-fragments [9][512] short8
    const unsigned short* __restrict__ xtb, // bf16 NHWC [N,H,W,CIN]
    float* __restrict__ out)                // [N,COUT,HO,WO] f32
{
    __shared__ short8 Adbuf[2][512];            // 16 KB A double buffer
    __shared__ uint4  Xr4[RROWS * RCOLS * 8];   // 59904 B halo region

    const int tid  = threadIdx.x;
    const int lane = tid & 63;
    const int wv   = tid >> 6;              // 0..7 -> ho row
    const int g    = lane >> 4;             // ci group
    const int pxw  = lane & 15;             // wo offset within wave
    const int ci0  = g * 8;

    // Bijective XCD chunk swizzle (512 % 8 == 0): 64 consecutive per XCD.
    const int raw = blockIdx.x;
    const int swz = (raw & 7) * 64 + (raw >> 3);
    const int n   = swz >> 7;               // 0..3
    const int r   = swz & 127;
    const int hb  = (r >> 3) << 3;          // 0..120 step 8
    const int wb  = (r & 7) << 4;           // 0..112 step 16
    const int ho  = hb + wv;
    const int wo  = wb + pxw;
    const int rowbase = hb - 5;
    const int colbase = wb - 5;

    const unsigned short* xb = xtb + (size_t)n * (H_ * W_ * CIN);
    const short8* wfq = (const short8*)wf;  // [9][512]
    char* XrB = (char*)Xr4;

    // ---- stage halo region (coalesced) + tap-0 A-fragments ----
    {
        const int NCHUNK = RROWS * RCOLS * 8;   // 3744
#pragma unroll
        for (int e = 0; e < 8; ++e) {
            int q = e * 512 + tid;
            if (q < NCHUNK) {
                int p = q >> 3, c = q & 7;
                int i = p / RCOLS, j = p - i * RCOLS;
                int sy = min(max(rowbase + i, 0), H_ - 1);
                int sx = min(max(colbase + j, 0), W_ - 1);
                const uint4 v = *(const uint4*)(xb + (sy * W_ + sx) * CIN + c * 8);
                *(uint4*)(XrB + reg_byteoff(p, c)) = v;
            }
        }
        Adbuf[0][tid] = wfq[tid];
    }

    f32x4 acc[4];
#pragma unroll
    for (int t = 0; t < 4; ++t) acc[t] = (f32x4){0.f, 0.f, 0.f, 0.f};

    const int pofs = ho * WO_ + wo;
    float npdy = offset[(n * 18 + 0) * (HO_ * WO_) + pofs];
    float npdx = offset[(n * 18 + 1) * (HO_ * WO_) + pofs];
    float npm  = mask  [(n * 9  + 0) * (HO_ * WO_) + pofs];

    __syncthreads();    // region + A0 ready

#pragma unroll
    for (int k = 0; k < K2_; ++k) {
        // A prefetch for next tap (write-late after MFMA; R6 discipline)
        short8 sA;
        if (k < K2_ - 1) sA = wfq[(k + 1) * 512 + tid];

        // consume np* for tap k
        const int KI = k / 3, KJ = k % 3;
        const float yy  = (float)(ho - 1 + KI) + npdy;
        const float xx  = (float)(wo - 1 + KJ) + npdx;
        const float y0f = floorf(yy), x0f = floorf(xx);
        const int   y0  = (int)y0f,  x0  = (int)x0f;
        const float fy  = yy - y0f,  fx  = xx - x0f;
        const bool yv0 = (y0 >= 0)  && (y0 < H_);
        const bool yv1 = (y0 >= -1) && (y0 < H_ - 1);
        const bool xv0 = (x0 >= 0)  && (x0 < W_);
        const bool xv1 = (x0 >= -1) && (x0 < W_ - 1);
        const float gy0 = (1.f - fy) * npm, gy1 = fy * npm;
        const float w00 = (yv0 && xv0) ? gy0 * (1.f - fx) : 0.f;
        const float w01 = (yv0 && xv1) ? gy0 * fx         : 0.f;
        const float w10 = (yv1 && xv0) ? gy1 * (1.f - fx) : 0.f;
        const float w11 = (yv1 && xv1) ? gy1 * fx         : 0.f;
        const int y0c = min(max(y0, 0), H_ - 1), y1c = min(max(y0 + 1, 0), H_ - 1);
        const int x0c = min(max(x0, 0), W_ - 1), x1c = min(max(x0 + 1, 0), W_ - 1);

        // params for next tap
        if (k < K2_ - 1) {
            npdy = offset[(n * 18 + 2 * (k + 1))     * (HO_ * WO_) + pofs];
            npdx = offset[(n * 18 + 2 * (k + 1) + 1) * (HO_ * WO_) + pofs];
            npm  = mask  [(n * 9  + (k + 1))         * (HO_ * WO_) + pofs];
        }

        // ---- 4 corners from LDS region (both ci halves), rare global fallback ----
        uint4 cva[4], cvb[4];   // [corner] kk=0 / kk=1
        const int cys[2] = { y0c, y1c };
        const int cxs[2] = { x0c, x1c };
#pragma unroll
        for (int cy_i = 0; cy_i < 2; ++cy_i) {
#pragma unroll
            for (int cx_i = 0; cx_i < 2; ++cx_i) {
                const int ci_ = cy_i * 2 + cx_i;
                const int cy = cys[cy_i], cx = cxs[cx_i];
                const int ry = cy - rowbase, rx = cx - colbase;
                const bool in = ((unsigned)ry < (unsigned)RROWS) &&
                                ((unsigned)rx < (unsigned)RCOLS);
                const int p = min(max(ry, 0), RROWS - 1) * RCOLS + min(max(rx, 0), RCOLS - 1);
                uint4 lv0 = *(const uint4*)(XrB + reg_byteoff(p, g));
                uint4 lv1 = *(const uint4*)(XrB + reg_byteoff(p, 4 + g));
                if (!__all((int)in)) {          // wave-uniform rare path
                    const unsigned short* gp = xb + (cy * W_ + cx) * CIN + ci0;
                    uint4 gv0 = *(const uint4*)(gp);
                    uint4 gv1 = *(const uint4*)(gp + 32);
                    if (!in) { lv0 = gv0; lv1 = gv1; }   // exec-masked per lane
                }
                cva[ci_] = lv0;
                cvb[ci_] = lv1;
            }
        }

        // ---- combine -> B fragments (bf16) ----
        union F8 { unsigned int u[4]; short8 s; } f0, f1;
        f0.u[0] = comb1(cva[0].x, cva[1].x, cva[2].x, cva[3].x, w00, w01, w10, w11);
        f0.u[1] = comb1(cva[0].y, cva[1].y, cva[2].y, cva[3].y, w00, w01, w10, w11);
        f0.u[2] = comb1(cva[0].z, cva[1].z, cva[2].z, cva[3].z, w00, w01, w10, w11);
        f0.u[3] = comb1(cva[0].w, cva[1].w, cva[2].w, cva[3].w, w00, w01, w10, w11);
        f1.u[0] = comb1(cvb[0].x, cvb[1].x, cvb[2].x, cvb[3].x, w00, w01, w10, w11);
        f1.u[1] = comb1(cvb[0].y, cvb[1].y, cvb[2].y, cvb[3].y, w00, w01, w10, w11);
        f1.u[2] = comb1(cvb[0].z, cvb[1].z, cvb[2].z, cvb[3].z, w00, w01, w10, w11);
        f1.u[3] = comb1(cvb[0].w, cvb[1].w, cvb[2].w, cvb[3].w, w00, w01, w10, w11);

        // ---- MFMA: 4 co-tiles x 2 k-halves ----
#pragma unroll
        for (int t = 0; t < 4; ++t) {
            const short8 A0 = Adbuf[k & 1][(t * 2 + 0) * 64 + lane];
            const short8 A1 = Adbuf[k & 1][(t * 2 + 1) * 64 + lane];
            acc[t] = __builtin_amdgcn_mfma_f32_16x16x32_bf16(A0, f0.s, acc[t], 0, 0, 0);
            acc[t] = __builtin_amdgcn_mfma_f32_16x16x32_bf16(A1, f1.s, acc[t], 0, 0, 0);
        }

        // write-late A-stage + single barrier per tap
        if (k < K2_ - 1) {
            Adbuf[(k + 1) & 1][tid] = sA;
            __syncthreads();
        }
    }

    // epilogue: D col = lane&15 (px/wo), row = g*4 + reg (co within tile t)
#pragma unroll
    for (int t = 0; t < 4; ++t) {
#pragma unroll
        for (int rr = 0; rr < 4; ++rr) {
            out[((size_t)(n * COUT + 16 * t + g * 4 + rr) * HO_ + ho) * WO_ + wo] = acc[t][rr];
        }
    }
}

// fp32 fallback (no workspace): known-correct round-1 structure.
__global__ __launch_bounds__(256, 4) void DeformConv2d_fallback(
    const float* __restrict__ x, const float* __restrict__ offset,
    const float* __restrict__ mask, const float* __restrict__ weight,
    float* __restrict__ out)
{
    __shared__ float W_lds[CIN * COUT];
    __shared__ float S_lds[CIN * 68];
    __shared__ float cfy[64], cfx[64], cm[64];
    __shared__ int   cy0[64], cx0[64];

    const int tid = threadIdx.x;
    const int raw = blockIdx.x;
    const int swz = (raw & 7) * 128 + (raw >> 3);
    const int n   = swz >> 8;
    const int r   = swz & 255;
    const int hb  = (r >> 3) << 2;
    const int wb  = (r & 7) << 4;
    const int tr = tid >> 4, tc = tid & 15;

    float acc[4][4];
#pragma unroll
    for (int j = 0; j < 4; ++j)
#pragma unroll
        for (int i = 0; i < 4; ++i) acc[j][i] = 0.f;

    for (int k = 0; k < K2_; ++k) {
        __syncthreads();
        if (tid < 64) {
            const int px = tid, ho = hb + (px >> 4), wo = wb + (px & 15);
            const int ki = k / 3, kj = k % 3;
            const float dy = offset[((n * 18 + 2 * k)     * HO_ + ho) * WO_ + wo];
            const float dx = offset[((n * 18 + 2 * k + 1) * HO_ + ho) * WO_ + wo];
            const float m  = mask  [((n * 9  + k)         * HO_ + ho) * WO_ + wo];
            const float yy = (float)(ho - 1 + ki) + dy;
            const float xx = (float)(wo - 1 + kj) + dx;
            const float y0f = floorf(yy), x0f = floorf(xx);
            cy0[px] = (int)y0f; cx0[px] = (int)x0f;
            cfy[px] = yy - y0f; cfx[px] = xx - x0f; cm[px] = m;
        }
#pragma unroll
        for (int e = 0; e < 16; ++e) {
            int i = e * 256 + tid, ci = i >> 6, co = i & 63;
            W_lds[ci * 64 + co] = weight[(co * CIN + ci) * K2_ + k];
        }
        __syncthreads();
#pragma unroll
        for (int e = 0; e < 16; ++e) {
            int i = e * 256 + tid, ci = i >> 6, px = i & 63;
            int   y0 = cy0[px], x0 = cx0[px];
            float fy = cfy[px], fx = cfx[px], m = cm[px];
            const float* xc = x + (size_t)(n * CIN + ci) * (H_ * W_);
            bool yv0 = (y0 >= 0)  && (y0 < H_);
            bool yv1 = (y0 >= -1) && (y0 < H_ - 1);
            bool xv0 = (x0 >= 0)  && (x0 < W_);
            bool xv1 = (x0 >= -1) && (x0 < W_ - 1);
            float v00 = (yv0 && xv0) ? xc[y0 * W_ + x0]           : 0.f;
            float v01 = (yv0 && xv1) ? xc[y0 * W_ + x0 + 1]       : 0.f;
            float v10 = (yv1 && xv0) ? xc[(y0 + 1) * W_ + x0]     : 0.f;
            float v11 = (yv1 && xv1) ? xc[(y0 + 1) * W_ + x0 + 1] : 0.f;
            float v = (v00 * (1.f - fy) + v10 * fy) * (1.f - fx)
                    + (v01 * (1.f - fy) + v11 * fy) * fx;
            S_lds[ci * 68 + px] = v * m;
        }
        __syncthreads();
#pragma unroll 8
        for (int ci = 0; ci < CIN; ++ci) {
            const float4 a = *(const float4*)&W_lds[ci * 64 + tr * 4];
            const float4 b = *(const float4*)&S_lds[ci * 68 + tc * 4];
            acc[0][0] += a.x * b.x; acc[0][1] += a.x * b.y; acc[0][2] += a.x * b.z; acc[0][3] += a.x * b.w;
            acc[1][0] += a.y * b.x; acc[1][1] += a.y * b.y; acc[1][2] += a.y * b.z; acc[1][3] += a.y * b.w;
            acc[2][0] += a.z * b.x; acc[2][1] += a.z * b.y; acc[2][2] += a.z * b.z; acc[2][3] += a.z * b.w;
            acc[3][0] += a.w * b.x; acc[3][1] += a.w * b.y; acc[3][2] += a.w * b.z; acc[3][3] += a.w * b.w;
        }
    }
    const int co0 = tr * 4, hoE = hb + (tc >> 2), woE = wb + (tc & 3) * 4;
#pragma unroll
    for (int j = 0; j < 4; ++j) {
        float4 v; v.x = acc[j][0]; v.y = acc[j][1]; v.z = acc[j][2]; v.w = acc[j][3];
        *(float4*)&out[((size_t)(n * COUT + co0 + j) * HO_ + hoE) * WO_ + woE] = v;
    }
}

extern "C" void kernel_launch(void* const* d_in, const int* in_sizes, int n_in,
                              void* d_out, int out_size, void* d_ws, size_t ws_size,
                              hipStream_t stream) {
    const float* x      = (const float*)d_in[0];
    const float* offset = (const float*)d_in[1];
    const float* mask   = (const float*)d_in[2];
    const float* weight = (const float*)d_in[3];
    float* out = (float*)d_out;

    const size_t wf_bytes = (size_t)K2_ * 8 * 64 * 8 * sizeof(unsigned short);        // 73728
    const size_t xt_bytes = (size_t)N_ * H_ * W_ * CIN * sizeof(unsigned short);      // 8 MB

    if (ws_size >= wf_bytes + xt_bytes) {
        unsigned short* wfb = (unsigned short*)d_ws;
        unsigned short* xtb = (unsigned short*)((char*)d_ws + wf_bytes);
        DeformConv2d_prep<<<4096 + 144, 256, 0, stream>>>(x, weight, xtb, wfb);
        DeformConv2d_mfma<<<512, 512, 0, stream>>>(offset, mask, wfb, xtb, out);
    } else {
        DeformConv2d_fallback<<<1024, 256, 0, stream>>>(x, offset, mask, weight, out);
    }
}